// Round 1
// baseline (1511.071 us; speedup 1.0000x reference)
//
#include <hip/hip_runtime.h>
#include <cstdint>
#include <cstddef>

typedef unsigned short u16;
typedef short bf16x8 __attribute__((ext_vector_type(8)));
typedef float f32x4 __attribute__((ext_vector_type(4)));

__device__ __forceinline__ float bf2f(u16 v) {
  union { unsigned int u; float f; } x; x.u = ((unsigned int)v) << 16; return x.f;
}
__device__ __forceinline__ u16 f2bf(float f) {
  union { float f; unsigned int u; } x; x.f = f;
  unsigned int r = (x.u + 0x7fffu + ((x.u >> 16) & 1u)) >> 16;
  return (u16)r;
}

__device__ __forceinline__ void async16(const u16* g, u16* lds) {
  __builtin_amdgcn_global_load_lds(
      (const __attribute__((address_space(1))) void*)g,
      (__attribute__((address_space(3))) void*)lds, 16, 0, 0);
}

// ---------------------------------------------------------------------------
// GEMM: C[M][N](stride ldc) = A[M][K](stride lda) @ Bt[N][K]^T (+ bias | + C)
// bf16 in, f32 acc, bf16 out.
// 256x256 tile, BK=64, 8 waves (2M x 4N), 8-phase schedule with counted
// vmcnt (T3+T4), setprio around MFMA clusters (T5), chunk^(row&7) XOR
// swizzle (T2; staging permutes per-lane GLOBAL chunk, LDS stays linear).
//
// LDS half-tile striping so each phase's quadrant (qm,qn) reads exactly
// A-half qm / B-half qn for EVERY wave:
//   A half h = rows with bit6==h (64-row stripes); phys idx = b7*64 + (r&63)
//   B half h = rows with bit5==h (32-row stripes); phys idx = (r>>6)*32 + (r&31)
// Per K-tile: 4 phases, quadrants (0,0)(0,1)(1,1)(1,0); each phase stages one
// half-tile of tile u+1 (order Ah0,Bh0,Bh1,Ah1) and waits vmcnt(4) -- queue
// simulation: steady-state outstanding stays 4-6 loads, all read deadlines
// met one barrier ahead, vmcnt never drains to 0 in the main loop.
// ---------------------------------------------------------------------------
#define BM 256
#define BN 256
#define BK 64

#define VMW(n) asm volatile("s_waitcnt vmcnt(" #n ")" ::: "memory")
#define BAR() do { asm volatile("" ::: "memory"); \
                   __builtin_amdgcn_s_barrier(); \
                   asm volatile("" ::: "memory"); } while (0)

template <bool ACC>
__global__ __launch_bounds__(512, 2) void gemm_bt(
    const u16* __restrict__ A, int lda,
    const u16* __restrict__ Bt,
    const float* __restrict__ bias,
    u16* __restrict__ C, int ldc,
    int M, int N, int K)
{
  __shared__ __align__(16) u16 As[2][BM * BK];   // 2 x 32 KiB
  __shared__ __align__(16) u16 Bs[2][BN * BK];   // 2 x 32 KiB
  const int tid = threadIdx.x;
  const int w   = tid >> 6;
  const int l   = tid & 63;
  const int wm  = w >> 2;            // 0..1 : 128-row band
  const int wn  = w & 3;             // 0..3 : 64-col band
  const int tRow = l & 15;
  const int quad = l >> 4;
  const int s7 = tRow & 7;
  const int bm = blockIdx.x, bn = blockIdx.y;

  // ---- staging addresses: pre-swizzled global chunk, linear LDS dest ----
  const int rsub = tid >> 3;                    // 0..63
  const int cLog = (tid & 7) ^ (rsub & 7);      // global 16B chunk this lane fetches
  const u16* ag[2][2]; const u16* bg[2][2];
  #pragma unroll
  for (int H = 0; H < 2; ++H) {
    #pragma unroll
    for (int j = 0; j < 2; ++j) {
      const int ra = H * 64 + j * 128 + rsub;            // A global row (64-stripes)
      ag[H][j] = A + (size_t)(bm * BM + ra) * lda + cLog * 8;
      const int p  = j * 64 + rsub;                      // phys row in half
      const int rb = (p & 31) + H * 32 + (p >> 5) * 64;  // B global row (32-stripes)
      bg[H][j] = Bt + (size_t)(bn * BN + rb) * K + cLog * 8;
    }
  }
  const int ldsW = w * 512;   // per-wave 1 KiB slot within an 8 KiB round

  f32x4 acc[8][4] = {};
  bf16x8 af[4][2], bf0[2][2], bf1[2][2];

#define STAGE_A(H, NB) do { \
    async16(ag[H][0], &As[NB][(H) * 8192 + ldsW]); \
    async16(ag[H][1], &As[NB][(H) * 8192 + 4096 + ldsW]); \
    ag[H][0] += BK; ag[H][1] += BK; } while (0)
#define STAGE_B(H, NB) do { \
    async16(bg[H][0], &Bs[NB][(H) * 8192 + ldsW]); \
    async16(bg[H][1], &Bs[NB][(H) * 8192 + 4096 + ldsW]); \
    bg[H][0] += BK; bg[H][1] += BK; } while (0)
#define READ_A(CB, H) do { \
    _Pragma("unroll") \
    for (int mt = 0; mt < 4; ++mt) { \
      _Pragma("unroll") \
      for (int kk = 0; kk < 2; ++kk) \
        af[mt][kk] = *(const bf16x8*)&As[CB][(H) * 8192 + \
            (wm * 64 + mt * 16 + tRow) * 64 + (((kk * 4 + quad) ^ s7)) * 8]; \
    } } while (0)
#define READ_B(CB, H, BF) do { \
    _Pragma("unroll") \
    for (int nt = 0; nt < 2; ++nt) { \
      _Pragma("unroll") \
      for (int kk = 0; kk < 2; ++kk) \
        BF[nt][kk] = *(const bf16x8*)&Bs[CB][(H) * 8192 + \
            (wn * 32 + nt * 16 + tRow) * 64 + (((kk * 4 + quad) ^ s7)) * 8]; \
    } } while (0)
#define MFMA_BLK(BF, MI0, NI0) do { \
    __builtin_amdgcn_s_setprio(1); \
    _Pragma("unroll") \
    for (int mt = 0; mt < 4; ++mt) { \
      _Pragma("unroll") \
      for (int nt = 0; nt < 2; ++nt) { \
        _Pragma("unroll") \
        for (int kk = 0; kk < 2; ++kk) \
          acc[(MI0) + mt][(NI0) + nt] = __builtin_amdgcn_mfma_f32_16x16x32_bf16( \
              af[mt][kk], BF[nt][kk], acc[(MI0) + mt][(NI0) + nt], 0, 0, 0); \
      } } \
    __builtin_amdgcn_s_setprio(0); } while (0)

  // prologue: stage tile 0 (issue order Ah0, Bh0, Bh1, Ah1)
  STAGE_A(0, 0); STAGE_B(0, 0); STAGE_B(1, 0); STAGE_A(1, 0);
  VMW(4);   // Ah0,Bh0 landed; Bh1,Ah1 (4 loads) still in flight
  BAR();

  const int NT = K / BK;
  for (int u = 0; u < NT - 1; ++u) {
    const int cb = u & 1, nb = cb ^ 1;
    // phase 0: quadrant (qm=0,qn=0); stage Ah0(u+1)
    READ_A(cb, 0); READ_B(cb, 0, bf0);
    STAGE_A(0, nb);
    VMW(4); BAR();
    MFMA_BLK(bf0, 0, 0);
    BAR();
    // phase 1: (0,1); A frags reused; stage Bh0(u+1)
    READ_B(cb, 1, bf1);
    STAGE_B(0, nb);
    VMW(4); BAR();
    MFMA_BLK(bf1, 0, 2);
    BAR();
    // phase 2: (1,1); B frags reused; stage Bh1(u+1)
    READ_A(cb, 1);
    STAGE_B(1, nb);
    VMW(4); BAR();
    MFMA_BLK(bf1, 4, 2);
    BAR();
    // phase 3: (1,0); zero ds_reads (af=Ah1, bf0 kept live); stage Ah1(u+1)
    STAGE_A(1, nb);
    VMW(4); BAR();
    MFMA_BLK(bf0, 4, 0);
    BAR();
  }
  { // last tile: no staging, drain 2 -> 0
    const int cb = (NT - 1) & 1;
    READ_A(cb, 0); READ_B(cb, 0, bf0);
    VMW(2); BAR();
    MFMA_BLK(bf0, 0, 0);
    BAR();
    READ_B(cb, 1, bf1);
    VMW(0); BAR();
    MFMA_BLK(bf1, 0, 2);
    BAR();
    READ_A(cb, 1);
    BAR();
    MFMA_BLK(bf1, 4, 2);
    BAR();
    MFMA_BLK(bf0, 4, 0);
  }
#undef STAGE_A
#undef STAGE_B
#undef READ_A
#undef READ_B
#undef MFMA_BLK

  // epilogue: C/D layout col = lane&15, row = quad*4 + reg (m89/m91 verified)
  const int crow0 = bm * BM + wm * 128;
  const int ccol0 = bn * BN + wn * 64;
  #pragma unroll
  for (int ni = 0; ni < 4; ++ni) {
    int col = ccol0 + ni * 16 + tRow;
    float bv = ACC ? 0.f : bias[col];
    #pragma unroll
    for (int mi = 0; mi < 8; ++mi) {
      int r0 = crow0 + mi * 16 + quad * 4;
      #pragma unroll
      for (int r = 0; r < 4; ++r) {
        size_t idx = (size_t)(r0 + r) * ldc + col;
        float v = acc[mi][ni][r] + bv;
        if (ACC) v += bf2f(C[idx]);
        C[idx] = f2bf(v);
      }
    }
  }
}

// ---------------------------------------------------------------------------
// Convert+transpose: dst[n][k] = f2bf(src[k*srcStride + col0 + n]),
// n in [0,C), k in [0,R). dst stride = R. grid (C/64, R/64), 256 thr.
// ---------------------------------------------------------------------------
__global__ __launch_bounds__(256) void transpose_f2bf(
    const float* __restrict__ src, u16* __restrict__ dst,
    int R, int C, int srcStride, int col0)
{
  __shared__ __align__(16) u16 tile[64][72];
  const int bx = blockIdx.x;  // over C/64 (dst rows)
  const int by = blockIdx.y;  // over R/64 (dst cols)
  const int t = threadIdx.x;
  const int r  = t >> 4;          // 0..15
  const int c4 = (t & 15) * 4;
  #pragma unroll
  for (int i = 0; i < 4; ++i) {
    int row = r + i * 16;
    f32x4 v = *(const f32x4*)&src[(size_t)(by * 64 + row) * srcStride + col0 + bx * 64 + c4];
    #pragma unroll
    for (int j = 0; j < 4; ++j) tile[row][c4 + j] = f2bf(v[j]);
  }
  __syncthreads();
  const int orow0 = t >> 3;       // 0..31
  const int oc8   = (t & 7) * 8;
  #pragma unroll
  for (int i = 0; i < 2; ++i) {
    int orow = orow0 + i * 32;    // source column
    u16 tmp[8];
    #pragma unroll
    for (int j = 0; j < 8; ++j) tmp[j] = tile[oc8 + j][orow];
    *(uint4*)&dst[(size_t)(bx * 64 + orow) * R + by * 64 + oc8] = *(uint4*)tmp;
  }
}

// ---------------------------------------------------------------------------
// Small helpers (all f32 inputs)
// ---------------------------------------------------------------------------
__global__ void cvt_f2bf(const float* __restrict__ s, u16* __restrict__ d) {
  size_t i = ((size_t)blockIdx.x * 256 + threadIdx.x) * 8;
  f32x4 a = *(const f32x4*)&s[i];
  f32x4 b = *(const f32x4*)&s[i + 4];
  u16 o[8];
  #pragma unroll
  for (int j = 0; j < 4; ++j) { o[j] = f2bf(a[j]); o[j + 4] = f2bf(b[j]); }
  *(uint4*)&d[i] = *(uint4*)o;
}

__global__ void mod_k(const float* __restrict__ ph, float* __restrict__ m, int n) {
  int i = blockIdx.x * 256 + threadIdx.x;
  if (i < n) { float p = ph[i]; m[i] = cosf(p) + sinf(p); }
}

__global__ void concat2_k(const float* __restrict__ a, const float* __restrict__ b,
                          float* __restrict__ d, int n) {
  int i = blockIdx.x * 256 + threadIdx.x;
  if (i < n) { d[i] = a[i]; d[n + i] = b[i]; }
}

// WcT[f][d] = sum_p pw[p][d][f] * mod[p][f]  (combined interference weight, bf16, transposed)
__global__ __launch_bounds__(256) void combine_path_k(
    const float* __restrict__ pw, const float* __restrict__ mod,
    u16* __restrict__ WcT, int D)
{
  __shared__ float tile[64][65];   // [d_local][f_local]
  const int bx = blockIdx.x;  // f tile
  const int by = blockIdx.y;  // d tile
  const int t = threadIdx.x;
  const int r  = t >> 4;          // 0..15
  const int c4 = (t & 15) * 4;
  float acc[4][4];
  #pragma unroll
  for (int i = 0; i < 4; ++i)
    #pragma unroll
    for (int j = 0; j < 4; ++j) acc[i][j] = 0.f;
  for (int p = 0; p < 2; ++p) {
    float m[4];
    #pragma unroll
    for (int j = 0; j < 4; ++j) m[j] = mod[p * D + bx * 64 + c4 + j];
    #pragma unroll
    for (int i = 0; i < 4; ++i) {
      int d = by * 64 + r + i * 16;
      f32x4 v = *(const f32x4*)&pw[((size_t)p * D + d) * D + bx * 64 + c4];
      #pragma unroll
      for (int j = 0; j < 4; ++j) acc[i][j] += v[j] * m[j];
    }
  }
  #pragma unroll
  for (int i = 0; i < 4; ++i)
    #pragma unroll
    for (int j = 0; j < 4; ++j) tile[r + i * 16][c4 + j] = acc[i][j];
  __syncthreads();
  const int fo0 = t >> 3;         // 0..31
  const int oc8 = (t & 7) * 8;
  #pragma unroll
  for (int i = 0; i < 2; ++i) {
    int fo = fo0 + i * 32;
    u16 tmp[8];
    #pragma unroll
    for (int j = 0; j < 8; ++j) tmp[j] = f2bf(tile[oc8 + j][fo]);
    *(uint4*)&WcT[(size_t)(bx * 64 + fo) * D + by * 64 + oc8] = *(uint4*)tmp;
  }
}

__global__ void combine_bias_k(const float* __restrict__ pb, const float* __restrict__ mod,
                               float* __restrict__ bc, int D) {
  int f = blockIdx.x * 256 + threadIdx.x;
  if (f < D) bc[f] = pb[f] * mod[f] + pb[D + f] * mod[D + f];
}

// h = (cos(pi*tanh(z2)) + sin(pi*tanh(z2))) * sigmoid(z1)
// zc is [M][2D]: z1 = cols [0,D), z2 = cols [D,2D).
__global__ __launch_bounds__(256) void superpose_k(
    const u16* __restrict__ zc, u16* __restrict__ h, int D)
{
  size_t idx = (size_t)blockIdx.x * 256 + threadIdx.x;   // over M*D/8 groups
  int grpPerRow = D / 8;
  size_t row = idx / grpPerRow;
  int cg = (int)(idx % grpPerRow);
  size_t zbase = row * (size_t)(2 * D) + cg * 8;
  uint4 v1 = *(const uint4*)&zc[zbase];
  uint4 v2 = *(const uint4*)&zc[zbase + D];
  const u16* p1 = (const u16*)&v1;
  const u16* p2 = (const u16*)&v2;
  u16 o[8];
  #pragma unroll
  for (int j = 0; j < 8; ++j) {
    float a = bf2f(p1[j]);
    float p = bf2f(p2[j]);
    float amp = 1.f / (1.f + __expf(-a));
    float ph = 3.14159265358979323f * tanhf(p);
    float s, c;
    __sincosf(ph, &s, &c);
    o[j] = f2bf((c + s) * amp);
  }
  *(uint4*)&h[row * D + cg * 8] = *(uint4*)o;
}

// out = LayerNorm(hin + delta) * g + b   (one block per row, D=2048; g,b f32)
template <bool F32OUT>
__global__ __launch_bounds__(256) void add_ln_k(
    const u16* __restrict__ hin, const u16* __restrict__ delta,
    const float* __restrict__ g, const float* __restrict__ b,
    void* __restrict__ outp, int D)
{
  const int row = blockIdx.x;
  const int t = threadIdx.x;
  const size_t base = (size_t)row * D;
  uint4 hv = *(const uint4*)&hin[base + t * 8];
  uint4 dv = *(const uint4*)&delta[base + t * 8];
  const u16* hp = (const u16*)&hv;
  const u16* dp = (const u16*)&dv;
  float x[8];
  float s = 0.f, s2 = 0.f;
  #pragma unroll
  for (int j = 0; j < 8; ++j) {
    x[j] = bf2f(hp[j]) + bf2f(dp[j]);
    s += x[j]; s2 += x[j] * x[j];
  }
  #pragma unroll
  for (int o = 32; o > 0; o >>= 1) {
    s  += __shfl_down(s, o, 64);
    s2 += __shfl_down(s2, o, 64);
  }
  __shared__ float ss[4], ss2[4];
  if ((t & 63) == 0) { ss[t >> 6] = s; ss2[t >> 6] = s2; }
  __syncthreads();
  float S  = ss[0] + ss[1] + ss[2] + ss[3];
  float S2 = ss2[0] + ss2[1] + ss2[2] + ss2[3];
  float mean = S / D;
  float var = S2 / D - mean * mean;
  float rstd = rsqrtf(var + 1e-5f);
  float y[8];
  #pragma unroll
  for (int j = 0; j < 8; ++j)
    y[j] = (x[j] - mean) * rstd * g[t * 8 + j] + b[t * 8 + j];
  if constexpr (F32OUT) {
    float* out = (float*)outp;
    f32x4 lo = {y[0], y[1], y[2], y[3]};
    f32x4 hi = {y[4], y[5], y[6], y[7]};
    *(f32x4*)&out[base + t * 8]     = lo;
    *(f32x4*)&out[base + t * 8 + 4] = hi;
  } else {
    u16* out = (u16*)outp;
    u16 o8[8];
    #pragma unroll
    for (int j = 0; j < 8; ++j) o8[j] = f2bf(y[j]);
    *(uint4*)&out[base + t * 8] = *(uint4*)o8;
  }
}

// ---------------------------------------------------------------------------
extern "C" void kernel_launch(void* const* d_in, const int* in_sizes, int n_in,
                              void* d_out, int out_size, void* d_ws, size_t ws_size,
                              hipStream_t stream) {
  // All reference dtypes are float32.
  const float* x      = (const float*)d_in[0];
  const float* amp_w  = (const float*)d_in[1];
  const float* amp_b  = (const float*)d_in[2];
  const float* ph_w   = (const float*)d_in[3];
  const float* ph_b   = (const float*)d_in[4];
  const float* ent_w  = (const float*)d_in[5];
  const float* ent_b  = (const float*)d_in[6];
  const float* ent_pw = (const float*)d_in[7];
  const float* ent_pb = (const float*)d_in[8];
  const float* path_w = (const float*)d_in[9];
  const float* path_b = (const float*)d_in[10];
  const float* phase  = (const float*)d_in[11];
  const float* ln3_g  = (const float*)d_in[12];
  const float* ln3_b  = (const float*)d_in[13];
  const float* ln4_g  = (const float*)d_in[14];
  const float* ln4_b  = (const float*)d_in[15];

  constexpr int D = 2048, PD = 8192, M = 4096, L = 2, PW = 2;
  constexpr int HPD = PD / 2;   // 4096 = slab width for entanglement layer

  // Workspace arena: 64 KiB floats + 112 MiB bf16 = well under 128 MiB.
  // Small buffers FIRST so any ws tightness hits large buffers we verified.
  char* p = (char*)d_ws;
  float* modf = (float*)p; p += (size_t)L * PW * D * sizeof(float);  // 32 KB
  float* bcf  = (float*)p; p += (size_t)2 * D * sizeof(float);       // 16 KB
  p = (char*)d_ws + 65536;                                           // pad to 64 KiB
  u16* h  = (u16*)p; p += (size_t)M * D * sizeof(u16);    // 16 MiB
  u16* t1 = (u16*)p; p += (size_t)M * D * sizeof(u16);    // 16 MiB
  u16* wT = (u16*)p; p += (size_t)HPD * D * sizeof(u16);  // 16 MiB (slab weight)
  u16* e  = (u16*)p; p += (size_t)M * PD * sizeof(u16);   // 64 MiB

  u16* xb = e;                      // bf16 copy of x (dead once zc computed)
  u16* zc = e + (size_t)M * D;      // [M][2D] fused amp/ph pre-activations

  dim3 b256(256);
  dim3 b512(512);

  mod_k<<<(L * PW * D) / 256, b256, 0, stream>>>(phase, modf, L * PW * D);
  cvt_f2bf<<<(M * D) / (256 * 8), b256, 0, stream>>>(x, xb);

  // superposition: zc = x @ [amp_w | ph_w] + [amp_b | ph_b] ; h = f(zc)
  transpose_f2bf<<<dim3(D / 64, D / 64), b256, 0, stream>>>(amp_w, wT, D, D, D, 0);
  transpose_f2bf<<<dim3(D / 64, D / 64), b256, 0, stream>>>(ph_w, wT + (size_t)D * D, D, D, D, 0);
  concat2_k<<<D / 256, b256, 0, stream>>>(amp_b, ph_b, bcf, D);
  gemm_bt<false><<<dim3(M / BM, (2 * D) / BN), b512, 0, stream>>>(
      xb, D, wT, bcf, zc, 2 * D, M, 2 * D, D);
  superpose_k<<<(M * D) / (256 * 8), b256, 0, stream>>>(zc, h, D);

  for (int l = 0; l < L; ++l) {
    // e = h @ ent_w[l] + ent_b[l]   [M, PD], in two N-slabs of HPD
    for (int s = 0; s < 2; ++s) {
      // wT[n][k] = ent_w[l][k][s*HPD + n],  n<HPD, k<D
      transpose_f2bf<<<dim3(HPD / 64, D / 64), b256, 0, stream>>>(
          ent_w + (size_t)l * D * PD, wT, D, HPD, PD, s * HPD);
      gemm_bt<false><<<dim3(M / BM, HPD / BN), b512, 0, stream>>>(
          h, D, wT, ent_b + (size_t)l * PD + s * HPD, e + s * HPD, PD, M, HPD, D);
    }
    // ent = e @ ent_pw[l] + ent_pb[l]   [M, D], in two K-slabs of HPD
    for (int s = 0; s < 2; ++s) {
      // wT[n][k] = ent_pw[l][s*HPD + k][n],  n<D, k<HPD
      transpose_f2bf<<<dim3(D / 64, HPD / 64), b256, 0, stream>>>(
          ent_pw + (size_t)l * PD * D + (size_t)s * HPD * D, wT, HPD, D, D, 0);
      if (s == 0)
        gemm_bt<false><<<dim3(M / BM, D / BN), b512, 0, stream>>>(
            e, PD, wT, ent_pb + (size_t)l * D, t1, D, M, D, HPD);
      else
        gemm_bt<true><<<dim3(M / BM, D / BN), b512, 0, stream>>>(
            e + HPD, PD, wT, bcf /*ignored*/, t1, D, M, D, HPD);
    }
    // h = LN(h + ent)
    add_ln_k<false><<<M, b256, 0, stream>>>(h, t1, ln3_g + (size_t)l * D, ln3_b + (size_t)l * D, h, D);
    // interf = h @ Wc + bc   (PW=2 pathways folded into one matrix)
    combine_path_k<<<dim3(D / 64, D / 64), b256, 0, stream>>>(
        path_w + (size_t)l * PW * D * D, modf + (size_t)l * PW * D, wT, D);
    combine_bias_k<<<D / 256, b256, 0, stream>>>(path_b + (size_t)l * PW * D, modf + (size_t)l * PW * D, bcf, D);
    gemm_bt<false><<<dim3(M / BM, D / BN), b512, 0, stream>>>(
        h, D, wT, bcf, t1, D, M, D, D);
    // h = LN(h + interf); final layer writes f32 d_out
    if (l == L - 1)
      add_ln_k<true><<<M, b256, 0, stream>>>(h, t1, ln4_g + (size_t)l * D, ln4_b + (size_t)l * D, d_out, D);
    else
      add_ln_k<false><<<M, b256, 0, stream>>>(h, t1, ln4_g + (size_t)l * D, ln4_b + (size_t)l * D, h, D);
  }
}

// Round 2
// 1417.522 us; speedup vs baseline: 1.0660x; 1.0660x over previous
//
#include <hip/hip_runtime.h>
#include <cstdint>
#include <cstddef>

typedef unsigned short u16;
typedef short bf16x8 __attribute__((ext_vector_type(8)));
typedef float f32x4 __attribute__((ext_vector_type(4)));

__device__ __forceinline__ float bf2f(u16 v) {
  union { unsigned int u; float f; } x; x.u = ((unsigned int)v) << 16; return x.f;
}
__device__ __forceinline__ u16 f2bf(float f) {
  union { float f; unsigned int u; } x; x.f = f;
  unsigned int r = (x.u + 0x7fffu + ((x.u >> 16) & 1u)) >> 16;
  return (u16)r;
}

__device__ __forceinline__ void async16(const u16* g, u16* lds) {
  __builtin_amdgcn_global_load_lds(
      (const __attribute__((address_space(1))) void*)g,
      (__attribute__((address_space(3))) void*)lds, 16, 0, 0);
}

template <int N> __device__ __forceinline__ void vmw() {
  if constexpr (N < 0) {}
  else if constexpr (N == 0)  asm volatile("s_waitcnt vmcnt(0)" ::: "memory");
  else if constexpr (N == 2)  asm volatile("s_waitcnt vmcnt(2)" ::: "memory");
  else if constexpr (N == 3)  asm volatile("s_waitcnt vmcnt(3)" ::: "memory");
  else if constexpr (N == 4)  asm volatile("s_waitcnt vmcnt(4)" ::: "memory");
  else if constexpr (N == 6)  asm volatile("s_waitcnt vmcnt(6)" ::: "memory");
  else if constexpr (N == 8)  asm volatile("s_waitcnt vmcnt(8)" ::: "memory");
  else if constexpr (N == 9)  asm volatile("s_waitcnt vmcnt(9)" ::: "memory");
  else if constexpr (N == 10) asm volatile("s_waitcnt vmcnt(10)" ::: "memory");
  else if constexpr (N == 12) asm volatile("s_waitcnt vmcnt(12)" ::: "memory");
}

#define BAR() do { asm volatile("" ::: "memory"); \
                   __builtin_amdgcn_s_barrier(); \
                   asm volatile("" ::: "memory"); } while (0)

// ---------------------------------------------------------------------------
// GEMM: C[M][N](stride ldc) = A[M][K](stride lda) @ Bt[N][K]^T (+ bias | + C)
// bf16 in, f32 acc, bf16 out. BM=256, BN = BNT (256 or 128), BK=64,
// 8 waves (2M x 4N), 4 quadrant phases per K-tile, counted vmcnt.
//
// Deep prefetch: during tile u, stage tile u+2 into the CURRENT buffer
// (u+2 and u share parity), each region staged in the phase AFTER its last
// read: Ah0+Bh0 at p1, Bh1 at p2, Ah1 at p3.  FIFO drain distances >= 5
// phases.  Steady waits (BNT=256): p0 vmcnt(10), p1 (12), p3 (12);
// (BNT=128): 8 / 9 / 9.  Tails specialize the drain.
// XOR swizzle: LDS phys chunk s of phys row p holds global chunk s^(p&7);
// staging pre-swizzles the per-lane GLOBAL chunk, LDS stays linear.
// ---------------------------------------------------------------------------
#define BM 256
#define BK 64

template <bool ACC, int BNT>
__global__ __launch_bounds__(512, 2) void gemm_bt(
    const u16* __restrict__ A, int lda,
    const u16* __restrict__ Bt,
    const float* __restrict__ bias,
    u16* __restrict__ C, int ldc,
    int M, int N, int K)
{
  constexpr int NIH   = BNT / 128;      // n-tiles per half per wave (2 or 1)
  constexpr int NI    = 2 * NIH;
  constexpr int JB    = BNT / 128;      // B wave-loads per half (2 or 1)
  constexpr int BHALF = BNT * 32;       // u16 per B half

  __shared__ __align__(16) u16 As[2][BM * BK];
  __shared__ __align__(16) u16 Bs[2][BNT * BK];

  const int tid = threadIdx.x;
  const int w   = tid >> 6;
  const int l   = tid & 63;
  const int wm  = w >> 2;            // 0..1 : 128-row band
  const int wn  = w & 3;             // 0..3 : (BNT/4)-col band
  const int tRow = l & 15;
  const int quad = l >> 4;
  const int s7 = tRow & 7;
  const int bm = blockIdx.x, bn = blockIdx.y;

  // ---- staging addresses: pre-swizzled global chunk, linear LDS dest ----
  const int rsub = tid >> 3;                    // 0..63
  const int cLog = (tid & 7) ^ (rsub & 7);      // global 16B chunk this lane fetches
  const u16* ag[2][2]; const u16* bg[2][JB];
  #pragma unroll
  for (int H = 0; H < 2; ++H) {
    #pragma unroll
    for (int j = 0; j < 2; ++j) {
      const int ra = H * 64 + j * 128 + rsub;            // A rows: 64-stripes on bit6
      ag[H][j] = A + (size_t)(bm * BM + ra) * lda + cLog * 8;
    }
    #pragma unroll
    for (int j = 0; j < JB; ++j) {
      const int p  = j * 64 + rsub;                      // phys row in half
      const int rb = (p / (16 * NIH)) * (32 * NIH) + H * (16 * NIH) + (p % (16 * NIH));
      bg[H][j] = Bt + (size_t)(bn * BNT + rb) * K + cLog * 8;
    }
  }
  const int ldsW = w * 512;   // per-wave 1 KiB slot within an 8 KiB round

  f32x4 acc[8][NI] = {};
  bf16x8 af[4][2], bf0[NIH][2], bf1[NIH][2];

#define STAGE_A(H, NB) do { \
    async16(ag[H][0], &As[NB][(H) * 8192 + ldsW]); \
    async16(ag[H][1], &As[NB][(H) * 8192 + 4096 + ldsW]); \
    ag[H][0] += BK; ag[H][1] += BK; } while (0)
#define STAGE_B(H, NB) do { \
    _Pragma("unroll") \
    for (int j = 0; j < JB; ++j) { \
      async16(bg[H][j], &Bs[NB][(H) * BHALF + j * 4096 + ldsW]); \
      bg[H][j] += BK; } } while (0)
#define READ_A(CB, H) do { \
    _Pragma("unroll") \
    for (int mt = 0; mt < 4; ++mt) { \
      _Pragma("unroll") \
      for (int kk = 0; kk < 2; ++kk) \
        af[mt][kk] = *(const bf16x8*)&As[CB][(H) * 8192 + \
            (wm * 64 + mt * 16 + tRow) * 64 + (((kk * 4 + quad) ^ s7)) * 8]; \
    } } while (0)
#define READ_B(CB, H, BF) do { \
    _Pragma("unroll") \
    for (int nt = 0; nt < NIH; ++nt) { \
      _Pragma("unroll") \
      for (int kk = 0; kk < 2; ++kk) \
        BF[nt][kk] = *(const bf16x8*)&Bs[CB][(H) * BHALF + \
            (wn * 16 * NIH + nt * 16 + tRow) * 64 + (((kk * 4 + quad) ^ s7)) * 8]; \
    } } while (0)
#define MFMA_BLK(BF, MI0, NI0) do { \
    __builtin_amdgcn_s_setprio(1); \
    _Pragma("unroll") \
    for (int mt = 0; mt < 4; ++mt) { \
      _Pragma("unroll") \
      for (int nt = 0; nt < NIH; ++nt) { \
        _Pragma("unroll") \
        for (int kk = 0; kk < 2; ++kk) \
          acc[(MI0) + mt][(NI0) + nt] = __builtin_amdgcn_mfma_f32_16x16x32_bf16( \
              af[mt][kk], BF[nt][kk], acc[(MI0) + mt][(NI0) + nt], 0, 0, 0); \
      } } \
    __builtin_amdgcn_s_setprio(0); } while (0)

  // one K-tile: 4 quadrant phases (0,0)(0,1)(1,1)(1,0); DOSTAGE stages tile
  // u+2 into the current buffer, each region right after its last reader.
#define TILE(P0, P1, P3, DOSTAGE) do { \
    const int cb = u & 1; \
    /* p0 */ \
    READ_A(cb, 0); READ_B(cb, 0, bf0); \
    vmw<P0>(); BAR(); \
    MFMA_BLK(bf0, 0, 0); \
    BAR(); \
    /* p1 */ \
    READ_B(cb, 1, bf1); \
    if (DOSTAGE) { STAGE_A(0, cb); STAGE_B(0, cb); } \
    vmw<P1>(); BAR(); \
    MFMA_BLK(bf1, 0, NIH); \
    BAR(); \
    /* p2 */ \
    READ_A(cb, 1); \
    if (DOSTAGE) { STAGE_B(1, cb); } \
    BAR(); \
    MFMA_BLK(bf1, 4, NIH); \
    BAR(); \
    /* p3 */ \
    if (DOSTAGE) { STAGE_A(1, cb); } \
    vmw<P3>(); BAR(); \
    MFMA_BLK(bf0, 4, 0); \
    BAR(); \
  } while (0)

  // wait constants (per-wave FIFO simulation; see header comment)
  constexpr int PRO = (BNT == 256) ? 12 : 9;
  constexpr int P0W = (BNT == 256) ? 10 : 8;
  constexpr int P1W = (BNT == 256) ? 12 : 9;
  constexpr int P3W = (BNT == 256) ? 12 : 9;
  constexpr int T1W = (BNT == 256) ? 8 : 6;
  constexpr int T3W = (BNT == 256) ? 4 : 3;

  // prologue: stage tiles 0 and 1 (issue order per tile: A0,B0 | B1 | A1)
  STAGE_A(0, 0); STAGE_B(0, 0); STAGE_B(1, 0); STAGE_A(1, 0);
  STAGE_A(0, 1); STAGE_B(0, 1); STAGE_B(1, 1); STAGE_A(1, 1);
  vmw<PRO>();   // drains tile0 Ah0,Bh0
  BAR();

  const int NT = K / BK;
  int u = 0;
  for (; u < NT - 2; ++u) { TILE(P0W, P1W, P3W, true); }
  { TILE(P0W, T1W, T3W, false); ++u; }
  { TILE(2, 0, -1, false); }

#undef TILE
#undef STAGE_A
#undef STAGE_B
#undef READ_A
#undef READ_B
#undef MFMA_BLK

  // epilogue: C/D layout col = lane&15, row = quad*4 + reg (m89/m91 verified)
  const int crow0 = bm * BM + wm * 128;
  const int ccol0 = bn * BNT + wn * (NIH * 32);
  #pragma unroll
  for (int ni = 0; ni < NI; ++ni) {
    int col = ccol0 + ni * 16 + tRow;
    float bv = ACC ? 0.f : bias[col];
    #pragma unroll
    for (int mi = 0; mi < 8; ++mi) {
      int r0 = crow0 + mi * 16 + quad * 4;
      #pragma unroll
      for (int r = 0; r < 4; ++r) {
        size_t idx = (size_t)(r0 + r) * ldc + col;
        float v = acc[mi][ni][r] + bv;
        if (ACC) v += bf2f(C[idx]);
        C[idx] = f2bf(v);
      }
    }
  }
}

// ---------------------------------------------------------------------------
// Convert+transpose: dst[n][k] = f2bf(src[k*srcStride + col0 + n]),
// n in [0,C), k in [0,R). dst stride = R. grid (C/64, R/64), 256 thr.
// ---------------------------------------------------------------------------
__global__ __launch_bounds__(256) void transpose_f2bf(
    const float* __restrict__ src, u16* __restrict__ dst,
    int R, int C, int srcStride, int col0)
{
  __shared__ __align__(16) u16 tile[64][72];
  const int bx = blockIdx.x;  // over C/64 (dst rows)
  const int by = blockIdx.y;  // over R/64 (dst cols)
  const int t = threadIdx.x;
  const int r  = t >> 4;          // 0..15
  const int c4 = (t & 15) * 4;
  #pragma unroll
  for (int i = 0; i < 4; ++i) {
    int row = r + i * 16;
    f32x4 v = *(const f32x4*)&src[(size_t)(by * 64 + row) * srcStride + col0 + bx * 64 + c4];
    #pragma unroll
    for (int j = 0; j < 4; ++j) tile[row][c4 + j] = f2bf(v[j]);
  }
  __syncthreads();
  const int orow0 = t >> 3;       // 0..31
  const int oc8   = (t & 7) * 8;
  #pragma unroll
  for (int i = 0; i < 2; ++i) {
    int orow = orow0 + i * 32;    // source column
    u16 tmp[8];
    #pragma unroll
    for (int j = 0; j < 8; ++j) tmp[j] = tile[oc8 + j][orow];
    *(uint4*)&dst[(size_t)(bx * 64 + orow) * R + by * 64 + oc8] = *(uint4*)tmp;
  }
}

// ---------------------------------------------------------------------------
// Small helpers (all f32 inputs)
// ---------------------------------------------------------------------------
__global__ void cvt_f2bf(const float* __restrict__ s, u16* __restrict__ d) {
  size_t i = ((size_t)blockIdx.x * 256 + threadIdx.x) * 8;
  f32x4 a = *(const f32x4*)&s[i];
  f32x4 b = *(const f32x4*)&s[i + 4];
  u16 o[8];
  #pragma unroll
  for (int j = 0; j < 4; ++j) { o[j] = f2bf(a[j]); o[j + 4] = f2bf(b[j]); }
  *(uint4*)&d[i] = *(uint4*)o;
}

__global__ void mod_k(const float* __restrict__ ph, float* __restrict__ m, int n) {
  int i = blockIdx.x * 256 + threadIdx.x;
  if (i < n) { float p = ph[i]; m[i] = cosf(p) + sinf(p); }
}

__global__ void concat2_k(const float* __restrict__ a, const float* __restrict__ b,
                          float* __restrict__ d, int n) {
  int i = blockIdx.x * 256 + threadIdx.x;
  if (i < n) { d[i] = a[i]; d[n + i] = b[i]; }
}

// WcT[f][d] = sum_p pw[p][d][f] * mod[p][f]  (combined interference weight, bf16, transposed)
__global__ __launch_bounds__(256) void combine_path_k(
    const float* __restrict__ pw, const float* __restrict__ mod,
    u16* __restrict__ WcT, int D)
{
  __shared__ float tile[64][65];   // [d_local][f_local]
  const int bx = blockIdx.x;  // f tile
  const int by = blockIdx.y;  // d tile
  const int t = threadIdx.x;
  const int r  = t >> 4;          // 0..15
  const int c4 = (t & 15) * 4;
  float acc[4][4];
  #pragma unroll
  for (int i = 0; i < 4; ++i)
    #pragma unroll
    for (int j = 0; j < 4; ++j) acc[i][j] = 0.f;
  for (int p = 0; p < 2; ++p) {
    float m[4];
    #pragma unroll
    for (int j = 0; j < 4; ++j) m[j] = mod[p * D + bx * 64 + c4 + j];
    #pragma unroll
    for (int i = 0; i < 4; ++i) {
      int d = by * 64 + r + i * 16;
      f32x4 v = *(const f32x4*)&pw[((size_t)p * D + d) * D + bx * 64 + c4];
      #pragma unroll
      for (int j = 0; j < 4; ++j) acc[i][j] += v[j] * m[j];
    }
  }
  #pragma unroll
  for (int i = 0; i < 4; ++i)
    #pragma unroll
    for (int j = 0; j < 4; ++j) tile[r + i * 16][c4 + j] = acc[i][j];
  __syncthreads();
  const int fo0 = t >> 3;         // 0..31
  const int oc8 = (t & 7) * 8;
  #pragma unroll
  for (int i = 0; i < 2; ++i) {
    int fo = fo0 + i * 32;
    u16 tmp[8];
    #pragma unroll
    for (int j = 0; j < 8; ++j) tmp[j] = f2bf(tile[oc8 + j][fo]);
    *(uint4*)&WcT[(size_t)(bx * 64 + fo) * D + by * 64 + oc8] = *(uint4*)tmp;
  }
}

__global__ void combine_bias_k(const float* __restrict__ pb, const float* __restrict__ mod,
                               float* __restrict__ bc, int D) {
  int f = blockIdx.x * 256 + threadIdx.x;
  if (f < D) bc[f] = pb[f] * mod[f] + pb[D + f] * mod[D + f];
}

// h = (cos(pi*tanh(z2)) + sin(pi*tanh(z2))) * sigmoid(z1)
// zc is [M][2D]: z1 = cols [0,D), z2 = cols [D,2D).
__global__ __launch_bounds__(256) void superpose_k(
    const u16* __restrict__ zc, u16* __restrict__ h, int D)
{
  size_t idx = (size_t)blockIdx.x * 256 + threadIdx.x;   // over M*D/8 groups
  int grpPerRow = D / 8;
  size_t row = idx / grpPerRow;
  int cg = (int)(idx % grpPerRow);
  size_t zbase = row * (size_t)(2 * D) + cg * 8;
  uint4 v1 = *(const uint4*)&zc[zbase];
  uint4 v2 = *(const uint4*)&zc[zbase + D];
  const u16* p1 = (const u16*)&v1;
  const u16* p2 = (const u16*)&v2;
  u16 o[8];
  #pragma unroll
  for (int j = 0; j < 8; ++j) {
    float a = bf2f(p1[j]);
    float p = bf2f(p2[j]);
    float amp = 1.f / (1.f + __expf(-a));
    float ph = 3.14159265358979323f * tanhf(p);
    float s, c;
    __sincosf(ph, &s, &c);
    o[j] = f2bf((c + s) * amp);
  }
  *(uint4*)&h[row * D + cg * 8] = *(uint4*)o;
}

// out = LayerNorm(hin + delta) * g + b   (one block per row, D=2048; g,b f32)
template <bool F32OUT>
__global__ __launch_bounds__(256) void add_ln_k(
    const u16* __restrict__ hin, const u16* __restrict__ delta,
    const float* __restrict__ g, const float* __restrict__ b,
    void* __restrict__ outp, int D)
{
  const int row = blockIdx.x;
  const int t = threadIdx.x;
  const size_t base = (size_t)row * D;
  uint4 hv = *(const uint4*)&hin[base + t * 8];
  uint4 dv = *(const uint4*)&delta[base + t * 8];
  const u16* hp = (const u16*)&hv;
  const u16* dp = (const u16*)&dv;
  float x[8];
  float s = 0.f, s2 = 0.f;
  #pragma unroll
  for (int j = 0; j < 8; ++j) {
    x[j] = bf2f(hp[j]) + bf2f(dp[j]);
    s += x[j]; s2 += x[j] * x[j];
  }
  #pragma unroll
  for (int o = 32; o > 0; o >>= 1) {
    s  += __shfl_down(s, o, 64);
    s2 += __shfl_down(s2, o, 64);
  }
  __shared__ float ss[4], ss2[4];
  if ((t & 63) == 0) { ss[t >> 6] = s; ss2[t >> 6] = s2; }
  __syncthreads();
  float S  = ss[0] + ss[1] + ss[2] + ss[3];
  float S2 = ss2[0] + ss2[1] + ss2[2] + ss2[3];
  float mean = S / D;
  float var = S2 / D - mean * mean;
  float rstd = rsqrtf(var + 1e-5f);
  float y[8];
  #pragma unroll
  for (int j = 0; j < 8; ++j)
    y[j] = (x[j] - mean) * rstd * g[t * 8 + j] + b[t * 8 + j];
  if constexpr (F32OUT) {
    float* out = (float*)outp;
    f32x4 lo = {y[0], y[1], y[2], y[3]};
    f32x4 hi = {y[4], y[5], y[6], y[7]};
    *(f32x4*)&out[base + t * 8]     = lo;
    *(f32x4*)&out[base + t * 8 + 4] = hi;
  } else {
    u16* out = (u16*)outp;
    u16 o8[8];
    #pragma unroll
    for (int j = 0; j < 8; ++j) o8[j] = f2bf(y[j]);
    *(uint4*)&out[base + t * 8] = *(uint4*)o8;
  }
}

// ---------------------------------------------------------------------------
extern "C" void kernel_launch(void* const* d_in, const int* in_sizes, int n_in,
                              void* d_out, int out_size, void* d_ws, size_t ws_size,
                              hipStream_t stream) {
  // All reference dtypes are float32.
  const float* x      = (const float*)d_in[0];
  const float* amp_w  = (const float*)d_in[1];
  const float* amp_b  = (const float*)d_in[2];
  const float* ph_w   = (const float*)d_in[3];
  const float* ph_b   = (const float*)d_in[4];
  const float* ent_w  = (const float*)d_in[5];
  const float* ent_b  = (const float*)d_in[6];
  const float* ent_pw = (const float*)d_in[7];
  const float* ent_pb = (const float*)d_in[8];
  const float* path_w = (const float*)d_in[9];
  const float* path_b = (const float*)d_in[10];
  const float* phase  = (const float*)d_in[11];
  const float* ln3_g  = (const float*)d_in[12];
  const float* ln3_b  = (const float*)d_in[13];
  const float* ln4_g  = (const float*)d_in[14];
  const float* ln4_b  = (const float*)d_in[15];

  constexpr int D = 2048, PD = 8192, M = 4096, L = 2, PW = 2;
  constexpr int HPD = PD / 2;   // 4096 = slab width for entanglement layer

  // Workspace arena: 64 KiB floats + 112 MiB bf16 = well under 128 MiB.
  char* p = (char*)d_ws;
  float* modf = (float*)p; p += (size_t)L * PW * D * sizeof(float);  // 32 KB
  float* bcf  = (float*)p; p += (size_t)2 * D * sizeof(float);       // 16 KB
  p = (char*)d_ws + 65536;                                           // pad to 64 KiB
  u16* h  = (u16*)p; p += (size_t)M * D * sizeof(u16);    // 16 MiB
  u16* t1 = (u16*)p; p += (size_t)M * D * sizeof(u16);    // 16 MiB
  u16* wT = (u16*)p; p += (size_t)HPD * D * sizeof(u16);  // 16 MiB (slab weight)
  u16* e  = (u16*)p; p += (size_t)M * PD * sizeof(u16);   // 64 MiB

  u16* xb = e;                      // bf16 copy of x (dead once zc computed)
  u16* zc = e + (size_t)M * D;      // [M][2D] fused amp/ph pre-activations

  dim3 b256(256);
  dim3 b512(512);

  mod_k<<<(L * PW * D) / 256, b256, 0, stream>>>(phase, modf, L * PW * D);
  cvt_f2bf<<<(M * D) / (256 * 8), b256, 0, stream>>>(x, xb);

  // superposition: zc = x @ [amp_w | ph_w] + [amp_b | ph_b] ; h = f(zc)
  transpose_f2bf<<<dim3(D / 64, D / 64), b256, 0, stream>>>(amp_w, wT, D, D, D, 0);
  transpose_f2bf<<<dim3(D / 64, D / 64), b256, 0, stream>>>(ph_w, wT + (size_t)D * D, D, D, D, 0);
  concat2_k<<<D / 256, b256, 0, stream>>>(amp_b, ph_b, bcf, D);
  gemm_bt<false, 256><<<dim3(M / BM, (2 * D) / 256), b512, 0, stream>>>(
      xb, D, wT, bcf, zc, 2 * D, M, 2 * D, D);
  superpose_k<<<(M * D) / (256 * 8), b256, 0, stream>>>(zc, h, D);

  for (int l = 0; l < L; ++l) {
    // e = h @ ent_w[l] + ent_b[l]   [M, PD], in two N-slabs of HPD
    for (int s = 0; s < 2; ++s) {
      // wT[n][k] = ent_w[l][k][s*HPD + n],  n<HPD, k<D
      transpose_f2bf<<<dim3(HPD / 64, D / 64), b256, 0, stream>>>(
          ent_w + (size_t)l * D * PD, wT, D, HPD, PD, s * HPD);
      gemm_bt<false, 256><<<dim3(M / BM, HPD / 256), b512, 0, stream>>>(
          h, D, wT, ent_b + (size_t)l * PD + s * HPD, e + s * HPD, PD, M, HPD, D);
    }
    // ent = e @ ent_pw[l] + ent_pb[l]   [M, D], in two K-slabs of HPD
    for (int s = 0; s < 2; ++s) {
      // wT[n][k] = ent_pw[l][s*HPD + k][n],  n<D, k<HPD
      transpose_f2bf<<<dim3(D / 64, HPD / 64), b256, 0, stream>>>(
          ent_pw + (size_t)l * PD * D + (size_t)s * HPD * D, wT, HPD, D, D, 0);
      if (s == 0)
        gemm_bt<false, 128><<<dim3(M / BM, D / 128), b512, 0, stream>>>(
            e, PD, wT, ent_pb + (size_t)l * D, t1, D, M, D, HPD);
      else
        gemm_bt<true, 128><<<dim3(M / BM, D / 128), b512, 0, stream>>>(
            e + HPD, PD, wT, bcf /*ignored*/, t1, D, M, D, HPD);
    }
    // h = LN(h + ent)
    add_ln_k<false><<<M, b256, 0, stream>>>(h, t1, ln3_g + (size_t)l * D, ln3_b + (size_t)l * D, h, D);
    // interf = h @ Wc + bc   (PW=2 pathways folded into one matrix)
    combine_path_k<<<dim3(D / 64, D / 64), b256, 0, stream>>>(
        path_w + (size_t)l * PW * D * D, modf + (size_t)l * PW * D, wT, D);
    combine_bias_k<<<D / 256, b256, 0, stream>>>(path_b + (size_t)l * PW * D, modf + (size_t)l * PW * D, bcf, D);
    gemm_bt<false, 128><<<dim3(M / BM, D / 128), b512, 0, stream>>>(
        h, D, wT, bcf, t1, D, M, D, D);
    // h = LN(h + interf); final layer writes f32 d_out
    if (l == L - 1)
      add_ln_k<true><<<M, b256, 0, stream>>>(h, t1, ln4_g + (size_t)l * D, ln4_b + (size_t)l * D, d_out, D);
    else
      add_ln_k<false><<<M, b256, 0, stream>>>(h, t1, ln4_g + (size_t)l * D, ln4_b + (size_t)l * D, h, D);
  }
}